// Round 2
// baseline (587.180 us; speedup 1.0000x reference)
//
#include <hip/hip_runtime.h>
#include <math.h>

#define NPOINTS (1 << 21)
#define LVL 16
#define TSIZE (1 << 19)
#define TMASK (TSIZE - 1)
#define PRIME2 2654435761u

typedef float f32x2 __attribute__((ext_vector_type(2)));
typedef float f32x4 __attribute__((ext_vector_type(4)));

struct ResArr {
    int   n[LVL];
    float fn[LVL];
};

__global__ __launch_bounds__(256) void hashgrid2d_kernel(
    const f32x2* __restrict__ xy,
    const f32x2* __restrict__ tables,
    f32x4* __restrict__ out,
    ResArr res)
{
    int p = blockIdx.x * blockDim.x + threadIdx.x;
    if (p >= NPOINTS) return;

    f32x2 pt = __builtin_nontemporal_load(&xy[p]);

    f32x4* o = out + (size_t)p * 8;

    #pragma unroll
    for (int k = 0; k < 8; ++k) {   // 2 levels per iteration -> one float4 store
        float f[4];
        #pragma unroll
        for (int j = 0; j < 2; ++j) {
            int l = 2 * k + j;
            int   N  = res.n[l];
            float fN = res.fn[l];

            float sx = pt.x * fN;
            float sy = pt.y * fN;
            float fx = floorf(sx);
            float fy = floorf(sy);
            float wx = sx - fx;
            float wy = sy - fy;
            int ix = (int)fx;
            int iy = (int)fy;

            // (i0 + d) % N with 0 <= i0 <= N (fp rounding edge included)
            int cx0 = (ix     >= N) ? ix     - N : ix;
            int cx1 = (ix + 1 >= N) ? ix + 1 - N : ix + 1;
            int cy0 = (iy     >= N) ? iy     - N : iy;
            int cy1 = (iy + 1 >= N) ? iy + 1 - N : iy + 1;

            unsigned hy0 = (unsigned)cy0 * PRIME2;
            unsigned hy1 = (unsigned)cy1 * PRIME2;
            int h00 = (int)(((unsigned)cx0 ^ hy0) & TMASK);
            int h10 = (int)(((unsigned)cx1 ^ hy0) & TMASK);
            int h01 = (int)(((unsigned)cx0 ^ hy1) & TMASK);
            int h11 = (int)(((unsigned)cx1 ^ hy1) & TMASK);

            const f32x2* tbl = tables + (size_t)l * TSIZE;
            f32x2 c00 = tbl[h00];
            f32x2 c10 = tbl[h10];
            f32x2 c01 = tbl[h01];
            f32x2 c11 = tbl[h11];

            float omx = 1.0f - wx, omy = 1.0f - wy;
            float f0x = c00.x * omx + c10.x * wx;
            float f0y = c00.y * omx + c10.y * wx;
            float f1x = c01.x * omx + c11.x * wx;
            float f1y = c01.y * omx + c11.y * wx;

            f[2 * j]     = f0x * omy + f1x * wy;
            f[2 * j + 1] = f0y * omy + f1y * wy;
        }
        f32x4 v = { f[0], f[1], f[2], f[3] };
        __builtin_nontemporal_store(v, o + k);
    }
}

extern "C" void kernel_launch(void* const* d_in, const int* in_sizes, int n_in,
                              void* d_out, int out_size, void* d_ws, size_t ws_size,
                              hipStream_t stream) {
    const f32x2* xy     = (const f32x2*)d_in[0];
    const f32x2* tables = (const f32x2*)d_in[1];
    f32x4* out = (f32x4*)d_out;

    ResArr res;
    double b = pow(2048.0 / 16.0, 1.0 / 15.0);
    for (int l = 0; l < LVL; ++l) {
        int N = (int)llround(16.0 * pow(b, (double)l));
        res.n[l]  = N;
        res.fn[l] = (float)N;
    }

    dim3 block(256);
    dim3 grid(NPOINTS / 256);
    hashgrid2d_kernel<<<grid, block, 0, stream>>>(xy, tables, out, res);
}

// Round 3
// 415.314 us; speedup vs baseline: 1.4138x; 1.4138x over previous
//
#include <hip/hip_runtime.h>
#include <math.h>

#define NPOINTS (1 << 21)
#define LVL 16
#define TSIZE (1 << 19)
#define TMASK (TSIZE - 1)
#define PRIME2 2654435761u

typedef float f32x2 __attribute__((ext_vector_type(2)));
typedef float f32x4 __attribute__((ext_vector_type(4)));

struct ResArr {
    int   n[LVL];
    float fn[LVL];
};

// 36 KB LDS (9-slot padded rows) -> 4 blocks/CU; __launch_bounds__(256,4)
// allows up to 128 VGPRs so the 32-load batches can stay in flight.
__global__ __launch_bounds__(256, 4) void hashgrid2d_kernel(
    const f32x2* __restrict__ xy,
    const f32x2* __restrict__ tables,
    f32x4* __restrict__ out,
    ResArr res)
{
    __shared__ f32x4 lds[256 * 9];   // 8 data + 1 pad per thread = 36 KB

    int tid = threadIdx.x;
    int p   = blockIdx.x * 256 + tid;

    f32x2 pt = __builtin_nontemporal_load(&xy[p]);

    #pragma unroll
    for (int b = 0; b < 2; ++b) {        // two batches of 8 levels
        f32x2 c[32];                     // 32 corner gathers in flight
        float wx[8], wy[8];

        #pragma unroll
        for (int j = 0; j < 8; ++j) {    // phase A: addresses + loads only
            int l = b * 8 + j;
            int   N  = res.n[l];
            float fN = res.fn[l];

            float sx = pt.x * fN;
            float sy = pt.y * fN;
            float fx = floorf(sx);
            float fy = floorf(sy);
            wx[j] = sx - fx;
            wy[j] = sy - fy;
            int ix = (int)fx;
            int iy = (int)fy;

            // (i0 + d) % N with 0 <= i0 <= N (fp rounding edge included)
            int cx0 = (ix     >= N) ? ix - N     : ix;
            int cx1 = (ix + 1 >= N) ? ix + 1 - N : ix + 1;
            int cy0 = (iy     >= N) ? iy - N     : iy;
            int cy1 = (iy + 1 >= N) ? iy + 1 - N : iy + 1;

            unsigned hy0 = (unsigned)cy0 * PRIME2;
            unsigned hy1 = (unsigned)cy1 * PRIME2;

            const f32x2* tbl = tables + (size_t)l * TSIZE;
            c[j * 4 + 0] = tbl[(int)(((unsigned)cx0 ^ hy0) & TMASK)];
            c[j * 4 + 1] = tbl[(int)(((unsigned)cx1 ^ hy0) & TMASK)];
            c[j * 4 + 2] = tbl[(int)(((unsigned)cx0 ^ hy1) & TMASK)];
            c[j * 4 + 3] = tbl[(int)(((unsigned)cx1 ^ hy1) & TMASK)];
        }

        #pragma unroll
        for (int q = 0; q < 4; ++q) {    // phase B: blend 2 levels -> one float4
            float f[4];
            #pragma unroll
            for (int j = 0; j < 2; ++j) {
                int lj = q * 2 + j;
                f32x2 c00 = c[lj * 4 + 0];
                f32x2 c10 = c[lj * 4 + 1];
                f32x2 c01 = c[lj * 4 + 2];
                f32x2 c11 = c[lj * 4 + 3];
                float omx = 1.0f - wx[lj], omy = 1.0f - wy[lj];
                float f0x = c00.x * omx + c10.x * wx[lj];
                float f0y = c00.y * omx + c10.y * wx[lj];
                float f1x = c01.x * omx + c11.x * wx[lj];
                float f1y = c01.y * omx + c11.y * wx[lj];
                f[j * 2 + 0] = f0x * omy + f1x * wy[lj];
                f[j * 2 + 1] = f0y * omy + f1y * wy[lj];
            }
            f32x4 v = { f[0], f[1], f[2], f[3] };
            lds[tid * 9 + b * 4 + q] = v;
        }
    }

    __syncthreads();

    // Coalesced NT stores: each instruction writes 64 lanes x 16 B = 1 KB
    // contiguous -> full 64 B lines, write-combine friendly.
    size_t base = (size_t)blockIdx.x * 2048;   // out4 index
    #pragma unroll
    for (int i = 0; i < 8; ++i) {
        int g = i * 256 + tid;                 // 0..2047
        f32x4 v = lds[(g >> 3) * 9 + (g & 7)];
        __builtin_nontemporal_store(v, &out[base + g]);
    }
}

extern "C" void kernel_launch(void* const* d_in, const int* in_sizes, int n_in,
                              void* d_out, int out_size, void* d_ws, size_t ws_size,
                              hipStream_t stream) {
    const f32x2* xy     = (const f32x2*)d_in[0];
    const f32x2* tables = (const f32x2*)d_in[1];
    f32x4* out = (f32x4*)d_out;

    ResArr res;
    double b = pow(2048.0 / 16.0, 1.0 / 15.0);
    for (int l = 0; l < LVL; ++l) {
        int N = (int)llround(16.0 * pow(b, (double)l));
        res.n[l]  = N;
        res.fn[l] = (float)N;
    }

    dim3 block(256);
    dim3 grid(NPOINTS / 256);
    hashgrid2d_kernel<<<grid, block, 0, stream>>>(xy, tables, out, res);
}